// Round 8
// baseline (71.754 us; speedup 1.0000x reference)
//
#include <hip/hip_runtime.h>
#include <hip/hip_bf16.h>

#define D_MODEL 1024
#define STATE_N 256
#define BATCH 4
#define SEQ_LEN 4096
#define M_TOTAL (BATCH * SEQ_LEN)   // 16384
#define NCHUNK 128
#define CHUNK (SEQ_LEN / NCHUNK)    // 32

typedef __attribute__((ext_vector_type(8))) short bf16x8;
typedef __attribute__((ext_vector_type(4))) short s16x4;
typedef __attribute__((ext_vector_type(2))) short s16x2;
typedef __attribute__((ext_vector_type(4))) float f32x4;

static __device__ inline short f2bf(float f) {
    union { float f; unsigned u; } v; v.f = f;
    unsigned r = v.u + 0x7FFFu + ((v.u >> 16) & 1u);
    return (short)(r >> 16);
}
static __device__ inline float bf2f(short s) {
    union { unsigned u; float f; } v;
    v.u = ((unsigned)(unsigned short)s) << 16;
    return v.f;
}
static __device__ inline float sigmoidf(float x) { return 1.0f / (1.0f + expf(-x)); }

#define GLOAD_LDS16(gp, lp)                                                     \
    __builtin_amdgcn_global_load_lds(                                           \
        (const __attribute__((address_space(1))) void*)(gp),                    \
        (__attribute__((address_space(3))) void*)(lp), 16, 0, 0)

#define WAITVM(N) asm volatile("s_waitcnt vmcnt(" #N ")" ::: "memory")
#define WAITLGKM0 asm volatile("s_waitcnt lgkmcnt(0)" ::: "memory")
#define BARRIER() do { __builtin_amdgcn_s_barrier(); asm volatile("" ::: "memory"); } while (0)

// ---------------- prep: Bw,Cw fp32->bf16 tiled + lambda-power table ----------------
// Bwt: [cb 2][kt 16][kc 8][col 128][8]   (gemm1 B-tile order, BK=64)
// Cwt: [cb 16][t 4][ksq 8][col 64][8]    (gemm2 B-tile order)
// W:   [i 32][n 256] = lam[n]^(31-i)
__global__ void prep(const float* __restrict__ Bw, const float* __restrict__ Cw,
                     const float* __restrict__ ll,
                     short* __restrict__ Bwt, short* __restrict__ Cwt,
                     float* __restrict__ W) {
    const int bx = blockIdx.x, tid = threadIdx.x;
    if (bx >= 256) {   // W table: 32 blocks
        const int i = bx - 256, n = tid;
        W[i * 256 + n] = powf(sigmoidf(ll[n]), (float)(31 - i));
        return;
    }
    const int g = bx * 256 + tid;   // 65536 total
    const float* s; short* d;
    if (g < 32768) {
        const int col = g & 127, kc = (g >> 7) & 7, kt = (g >> 10) & 15, cb = g >> 14;
        s = Bw + (size_t)(cb * 128 + col) * D_MODEL + kt * 64 + kc * 8;
        d = Bwt + (size_t)g * 8;
    } else {
        const int h = g - 32768;
        const int col = h & 63, ksq = (h >> 6) & 7, tt = (h >> 9) & 3, cb = h >> 11;
        s = Cw + (size_t)(cb * 64 + col) * STATE_N + tt * 64 + ksq * 8;
        d = Cwt + (size_t)h * 8;
    }
    const f32x4 v0 = *(const f32x4*)s;
    const f32x4 v1 = *(const f32x4*)(s + 4);
    bf16x8 r;
    #pragma unroll
    for (int q = 0; q < 4; ++q) { r[q] = f2bf(v0[q]); r[4 + q] = f2bf(v1[q]); }
    *(bf16x8*)d = r;
}

// ---------------- GEMM1: Bu[m][n] = u[m][:].Bw[n][:], fused chunk-end scan ----------------
// BM=64, BN=128, BK=64, 16 iters. A reg-staged fp32->bf16 (3 reg sets, ds_write
// after barrier), B gload_lds from tiled Bwt (3 LDS bufs). Counted vmcnt.
__global__ __launch_bounds__(256, 2) void gemm1(const float* __restrict__ u,
                                                const short* __restrict__ Bwt,
                                                const float* __restrict__ W,
                                                short* __restrict__ Bu,
                                                float* __restrict__ ends) {
    __shared__ short Ash[2][64 * 64];       // 8KB/buf: [row][8 chunks of 8, XOR-swz]
    __shared__ short Bsh[3][8 * 128 * 8];   // 16KB/buf: [kc][col][8]
    const int tid = threadIdx.x;
    const int lane = tid & 63, wave = tid >> 6;
    const int lr = lane & 15, kq = lane >> 4;
    const int wr = wave >> 1, wc = wave & 1;
    const int wg = ((blockIdx.x & 7) << 6) + (blockIdx.x >> 3);  // 512 = 8*64 bijective
    const int cb = wg & 1, strip = wg >> 1;
    const int m0 = strip * 64, n0 = cb * 128;

    const int a_r = tid >> 4, a_k = (tid & 15) * 4;
    const float* au = u + (size_t)m0 * D_MODEL + (size_t)a_r * D_MODEL + a_k;
    const int a_ch = (tid & 15) >> 1, a_half = (tid & 1) * 4;
    const short* bg = Bwt + (size_t)cb * 16 * 8192;

    f32x4 acc[2][4] = {};
    f32x4 ar0[4], ar1[4], ar2[4];

    #define LOADA(SET, KT)                                                       \
        do { _Pragma("unroll")                                                   \
             for (int i = 0; i < 4; ++i)                                         \
                 SET[i] = *(const f32x4*)(au + (size_t)i * 16 * D_MODEL + (KT) * 64); } while (0)
    #define WRITEA(BUF, SET)                                                     \
        do { _Pragma("unroll")                                                   \
             for (int i = 0; i < 4; ++i) {                                       \
                 const int row = i * 16 + a_r;                                   \
                 s16x4 wv;                                                       \
                 _Pragma("unroll")                                               \
                 for (int e = 0; e < 4; ++e) wv[e] = f2bf(SET[i][e]);            \
                 *(s16x4*)&Ash[BUF][(row * 8 + (a_ch ^ (row & 7))) * 8 + a_half] = wv; \
             } } while (0)
    #define STAGEB(BUF, KT)                                                      \
        do { const short* bs = bg + (size_t)(KT) * 8192;                         \
             _Pragma("unroll")                                                   \
             for (int q = 0; q < 4; ++q)                                         \
                 GLOAD_LDS16(bs + (q * 256 + tid) * 8,                           \
                             (char*)&Bsh[BUF][0] + (q * 256 + wave * 64) * 16); } while (0)

    LOADA(ar0, 0);
    WAITVM(0);
    WRITEA(0, ar0);
    STAGEB(0, 0);
    LOADA(ar1, 1);
    STAGEB(1, 1);
    LOADA(ar2, 2);
    WAITLGKM0;

    #pragma unroll
    for (int t = 0; t < 16; ++t) {
        if (t < 14)      { WAITVM(8); }
        else if (t == 14){ WAITVM(4); }
        else             { WAITVM(0); }
        BARRIER();
        if (t < 15) {
            if (((t + 1) % 3) == 0)      WRITEA((t + 1) & 1, ar0);
            else if (((t + 1) % 3) == 1) WRITEA((t + 1) & 1, ar1);
            else                         WRITEA((t + 1) & 1, ar2);
        }
        bf16x8 af[2][2], bfr[2][4];
        #pragma unroll
        for (int ks = 0; ks < 2; ++ks) {
            #pragma unroll
            for (int i = 0; i < 2; ++i) {
                const int row = wr * 32 + i * 16 + lr;
                af[ks][i] = *(const bf16x8*)&Ash[t & 1][(row * 8 + ((ks * 4 + kq) ^ (row & 7))) * 8];
            }
            #pragma unroll
            for (int j = 0; j < 4; ++j)
                bfr[ks][j] = *(const bf16x8*)&Bsh[t % 3][((ks * 4 + kq) * 128 + wc * 64 + j * 16 + lr) * 8];
        }
        if (t + 2 <= 15) STAGEB((t + 2) % 3, t + 2);
        if (t + 3 <= 15) {
            if (((t + 3) % 3) == 0)      LOADA(ar0, t + 3);
            else if (((t + 3) % 3) == 1) LOADA(ar1, t + 3);
            else                         LOADA(ar2, t + 3);
        }
        #pragma unroll
        for (int ks = 0; ks < 2; ++ks)
            #pragma unroll
            for (int i = 0; i < 2; ++i)
                #pragma unroll
                for (int j = 0; j < 4; ++j)
                    acc[i][j] = __builtin_amdgcn_mfma_f32_16x16x32_bf16(bfr[ks][j], af[ks][i], acc[i][j], 0, 0, 0);
    }
    #undef LOADA
    #undef WRITEA
    #undef STAGEB

    #pragma unroll
    for (int i = 0; i < 2; ++i) {
        const int m = m0 + wr * 32 + i * 16 + lr;
        #pragma unroll
        for (int j = 0; j < 4; ++j) {
            const int n = n0 + wc * 64 + j * 16 + kq * 4;
            s16x4 st;
            #pragma unroll
            for (int r = 0; r < 4; ++r) st[r] = f2bf(acc[i][j][r]);
            *(s16x4*)(Bu + (size_t)m * STATE_N + n) = st;
        }
    }

    // fused chunk-end reduce: ends[cg][n] = sum_row lam^(31-row)*Bu
    float part[4][4];
    #pragma unroll
    for (int j = 0; j < 4; ++j) {
        const int nb = n0 + wc * 64 + j * 16 + kq * 4;
        const f32x4 w0 = *(const f32x4*)(W + (size_t)lr * 256 + nb);
        const f32x4 w1 = *(const f32x4*)(W + (size_t)(16 + lr) * 256 + nb);
        #pragma unroll
        for (int r = 0; r < 4; ++r)
            part[j][r] = w0[r] * acc[0][j][r] + w1[r] * acc[1][j][r];
    }
    #pragma unroll
    for (int m = 1; m <= 8; m <<= 1)
        #pragma unroll
        for (int j = 0; j < 4; ++j)
            #pragma unroll
            for (int r = 0; r < 4; ++r)
                part[j][r] += __shfl_xor(part[j][r], m, 64);
    if (lr == 0) {
        const int cg = strip * 2 + wr;
        #pragma unroll
        for (int j = 0; j < 4; ++j) {
            f32x4 e;
            #pragma unroll
            for (int r = 0; r < 4; ++r) e[r] = part[j][r];
            *(f32x4*)(ends + (size_t)cg * STATE_N + n0 + wc * 64 + j * 16 + kq * 4) = e;
        }
    }
}

// ---------------- GEMM2 (fused scan): h = scan(Bu), y = h.Cw^T + D*u ----------------
// Block 64r x 64c. Stage Bu-tile (A) + Cwt (B) up front; in-LDS seeded scan over
// the 2 chunks this block covers (thread owns a (chunk-half, col-pair) chain);
// then 4 x {counted vmcnt + barrier + MFMA}; vector epilogue.
__global__ __launch_bounds__(256) void gemm2(const short* __restrict__ Bu,
                                             const short* __restrict__ Cwt,
                                             const float* __restrict__ ll,
                                             const float* __restrict__ carries,
                                             const float* __restrict__ u,
                                             const float* __restrict__ Dv,
                                             float* __restrict__ y) {
    __shared__ short Ash[4][64 * 64];      // [tile][row][64 shorts], chunk-XOR swz
    __shared__ short Bsh[4][8 * 64 * 8];   // [tile][ksq][col][8]
    const int tid = threadIdx.x;
    const int lane = tid & 63, wave = tid >> 6;
    const int lr = lane & 15, kq = lane >> 4;
    const int wr = wave >> 1, wc = wave & 1;
    const int wg = ((blockIdx.x & 7) << 9) + (blockIdx.x >> 3);  // 4096 = 8*512 bijective
    const int cb = wg & 15, strip = wg >> 4;
    const int m0 = strip * 64, n0 = cb * 64;

    // scan chain assignment: thread -> (chunk-half, col-pair)
    const int ch = tid >> 7;                 // rows [ch*32, ch*32+32)
    const int cp = tid & 127;                // cols 2cp, 2cp+1 (global n = 2cp)
    const int st = cp >> 5;                  // A-tile holding these cols
    const int c0 = (2 * cp) & 63;            // within-tile col (even)
    const int scc = c0 >> 3, scw = c0 & 7;

    // plain reg loads (float anywhere in prologue; counts handled conservatively)
    const float2 lraw = *(const float2*)(ll + 2 * cp);
    const float2 car2 = *(const float2*)(carries + (size_t)(strip * 2 + ch) * STATE_N + 2 * cp);

    const int aslot0 = wave * 128 + lane, aslot1 = aslot0 + 64;
    const int arow0 = aslot0 >> 3, arow1 = aslot1 >> 3;
    const int ac = lane & 7;
    const short* ag0 = Bu + (size_t)(m0 + arow0) * STATE_N + ((ac ^ (arow0 & 7)) << 3);
    const short* ag1 = Bu + (size_t)(m0 + arow1) * STATE_N + ((ac ^ (arow1 & 7)) << 3);
    const short* bg = Cwt + (size_t)cb * 4 * 8 * 64 * 8;

    // A stages (8 instrs) then B stages (8 instrs) — intrinsics keep program order
    #pragma unroll
    for (int t = 0; t < 4; ++t) {
        GLOAD_LDS16(ag0 + t * 64, (char*)&Ash[t][0] + aslot0 * 16);
        GLOAD_LDS16(ag1 + t * 64, (char*)&Ash[t][0] + aslot1 * 16);
    }
    #pragma unroll
    for (int t = 0; t < 4; ++t) {
        const short* bs = bg + (size_t)t * 4096;
        GLOAD_LDS16(bs + ((wave * 2 + 0) * 64 + lane) * 8,
                    (char*)&Bsh[t][0] + (wave * 128 + lane) * 16);
        GLOAD_LDS16(bs + ((wave * 2 + 1) * 64 + lane) * 8,
                    (char*)&Bsh[t][0] + (wave * 128 + 64 + lane) * 16);
    }

    WAITVM(8);          // all A tiles landed (<=2 plain loads can only precede them)
    BARRIER();

    // ---- in-LDS seeded scan (B loads still in flight underneath) ----
    {
        const float lam0 = sigmoidf(lraw.x), lam1 = sigmoidf(lraw.y);
        s16x2 rv[32];
        #pragma unroll
        for (int i = 0; i < 32; ++i)
            rv[i] = *(const s16x2*)&Ash[st][(ch * 32 + i) * 64 + ((scc ^ (i & 7)) << 3) + scw];
        float h0 = car2.x, h1 = car2.y;
        #pragma unroll
        for (int i = 0; i < 32; ++i) {
            h0 = fmaf(lam0, h0, bf2f(rv[i][0]));
            h1 = fmaf(lam1, h1, bf2f(rv[i][1]));
            s16x2 o; o[0] = f2bf(h0); o[1] = f2bf(h1);
            rv[i] = o;
        }
        #pragma unroll
        for (int i = 0; i < 32; ++i)
            *(s16x2*)&Ash[st][(ch * 32 + i) * 64 + ((scc ^ (i & 7)) << 3) + scw] = rv[i];
    }
    WAITLGKM0;
    BARRIER();

    f32x4 acc[2][2] = {};
    #pragma unroll
    for (int t = 0; t < 4; ++t) {
        if (t == 0)      { WAITVM(6); }   // B-tile t landed (conservative counts)
        else if (t == 1) { WAITVM(4); }
        else if (t == 2) { WAITVM(2); }
        else             { WAITVM(0); }
        BARRIER();
        bf16x8 af[2][2], bfr[2][2];
        #pragma unroll
        for (int ks = 0; ks < 2; ++ks) {
            #pragma unroll
            for (int i = 0; i < 2; ++i) {
                const int row = wr * 32 + i * 16 + lr;
                af[i][ks] = *(const bf16x8*)&Ash[t][row * 64 + ((((ks << 2) | kq) ^ (row & 7)) << 3)];
            }
            #pragma unroll
            for (int j = 0; j < 2; ++j)
                bfr[j][ks] = *(const bf16x8*)&Bsh[t][((ks << 2) | kq) * 512 + (wc * 32 + j * 16 + lr) * 8];
        }
        #pragma unroll
        for (int ks = 0; ks < 2; ++ks)
            #pragma unroll
            for (int i = 0; i < 2; ++i)
                #pragma unroll
                for (int j = 0; j < 2; ++j)
                    acc[i][j] = __builtin_amdgcn_mfma_f32_16x16x32_bf16(bfr[j][ks], af[i][ks], acc[i][j], 0, 0, 0);
    }

    #pragma unroll
    for (int i = 0; i < 2; ++i) {
        const int m = m0 + wr * 32 + i * 16 + lr;
        #pragma unroll
        for (int j = 0; j < 2; ++j) {
            const int n = n0 + wc * 32 + j * 16 + kq * 4;
            const size_t o = (size_t)m * D_MODEL + n;
            const f32x4 uv = *(const f32x4*)(u + o);
            const f32x4 dv = *(const f32x4*)(Dv + n);
            f32x4 rv;
            #pragma unroll
            for (int q = 0; q < 4; ++q) rv[q] = fmaf(dv[q], uv[q], acc[i][j][q]);
            *(f32x4*)(y + o) = rv;
        }
    }
}

// ---------------- Scan pass 2: carry scan across chunks ----------------
__global__ void scan_carry(const float* __restrict__ ends,
                           const float* __restrict__ log_lambda,
                           float* __restrict__ carries) {
    const int n = threadIdx.x;
    const int b = blockIdx.x;
    const float lam = sigmoidf(log_lambda[n]);
    const float lamC = powf(lam, (float)CHUNK);
    float carry = 0.0f;
    #pragma unroll 16
    for (int c = 0; c < NCHUNK; ++c) {
        const size_t o = ((size_t)(b * NCHUNK + c)) * STATE_N + n;
        carries[o] = carry;
        carry = fmaf(lamC, carry, ends[o]);
    }
}

extern "C" void kernel_launch(void* const* d_in, const int* in_sizes, int n_in,
                              void* d_out, int out_size, void* d_ws, size_t ws_size,
                              hipStream_t stream) {
    const float* u  = (const float*)d_in[0];
    const float* ll = (const float*)d_in[1];
    const float* Bw = (const float*)d_in[2];
    const float* Cw = (const float*)d_in[3];
    const float* Dv = (const float*)d_in[4];
    float* y = (float*)d_out;

    char* ws = (char*)d_ws;
    size_t off = 0;
    short* Bwt = (short*)(ws + off); off += (size_t)STATE_N * D_MODEL * 2;      // 512 KB
    short* Cwt = (short*)(ws + off); off += (size_t)D_MODEL * STATE_N * 2;      // 512 KB
    float* W   = (float*)(ws + off); off += (size_t)32 * STATE_N * 4;           // 32 KB
    short* Bu  = (short*)(ws + off); off += (size_t)M_TOTAL * STATE_N * 2;      // 8 MB
    float* ends = (float*)(ws + off); off += (size_t)BATCH * NCHUNK * STATE_N * 4;
    float* carries = (float*)(ws + off);

    prep<<<288, 256, 0, stream>>>(Bw, Cw, ll, Bwt, Cwt, W);
    gemm1<<<512, 256, 0, stream>>>(u, Bwt, W, Bu, ends);
    scan_carry<<<BATCH, STATE_N, 0, stream>>>(ends, ll, carries);
    gemm2<<<4096, 256, 0, stream>>>(Bu, Cwt, ll, carries, u, Dv, y);
}

// Round 9
// 69.827 us; speedup vs baseline: 1.0276x; 1.0276x over previous
//
#include <hip/hip_runtime.h>
#include <hip/hip_bf16.h>

#define D_MODEL 1024
#define STATE_N 256
#define BATCH 4
#define SEQ_LEN 4096
#define M_TOTAL (BATCH * SEQ_LEN)   // 16384
#define NCHUNK 128
#define CHUNK (SEQ_LEN / NCHUNK)    // 32

typedef __attribute__((ext_vector_type(8))) short bf16x8;
typedef __attribute__((ext_vector_type(4))) short s16x4;
typedef __attribute__((ext_vector_type(2))) short s16x2;
typedef __attribute__((ext_vector_type(4))) float f32x4;

static __device__ inline short f2bf(float f) {
    union { float f; unsigned u; } v; v.f = f;
    unsigned r = v.u + 0x7FFFu + ((v.u >> 16) & 1u);
    return (short)(r >> 16);
}
static __device__ inline float bf2f(short s) {
    union { unsigned u; float f; } v;
    v.u = ((unsigned)(unsigned short)s) << 16;
    return v.f;
}
static __device__ inline float sigmoidf(float x) { return 1.0f / (1.0f + expf(-x)); }

#define GLOAD_LDS16(gp, lp)                                                     \
    __builtin_amdgcn_global_load_lds(                                           \
        (const __attribute__((address_space(1))) void*)(gp),                    \
        (__attribute__((address_space(3))) void*)(lp), 16, 0, 0)

#define WAITVM0   asm volatile("s_waitcnt vmcnt(0)" ::: "memory")
#define WAITLGKM0 asm volatile("s_waitcnt lgkmcnt(0)" ::: "memory")
#define BARRIER() do { __builtin_amdgcn_s_barrier(); asm volatile("" ::: "memory"); } while (0)

// ---------------- prep: Bw,Cw fp32->bf16 tiled + lambda-power table ----------------
// Bwt: [cb 2][kt 16][kc 8][col 128][8]   (gemm1 B frag order, BK=64)
// Cwt: [cb 16][t 4][ksq 8][col 64][8]    (gemm2 B frag order)
// W:   [i 32][n 256] = lam[n]^(31-i)
__global__ void prep(const float* __restrict__ Bw, const float* __restrict__ Cw,
                     const float* __restrict__ ll,
                     short* __restrict__ Bwt, short* __restrict__ Cwt,
                     float* __restrict__ W) {
    const int bx = blockIdx.x, tid = threadIdx.x;
    if (bx >= 256) {   // W table: 32 blocks
        const int i = bx - 256, n = tid;
        W[i * 256 + n] = powf(sigmoidf(ll[n]), (float)(31 - i));
        return;
    }
    const int g = bx * 256 + tid;   // 65536 total
    const float* s; short* d;
    if (g < 32768) {
        const int col = g & 127, kc = (g >> 7) & 7, kt = (g >> 10) & 15, cb = g >> 14;
        s = Bw + (size_t)(cb * 128 + col) * D_MODEL + kt * 64 + kc * 8;
        d = Bwt + (size_t)g * 8;
    } else {
        const int h = g - 32768;
        const int col = h & 63, ksq = (h >> 6) & 7, tt = (h >> 9) & 3, cb = h >> 11;
        s = Cw + (size_t)(cb * 64 + col) * STATE_N + tt * 64 + ksq * 8;
        d = Cwt + (size_t)h * 8;
    }
    const f32x4 v0 = *(const f32x4*)s;
    const f32x4 v1 = *(const f32x4*)(s + 4);
    bf16x8 r;
    #pragma unroll
    for (int q = 0; q < 4; ++q) { r[q] = f2bf(v0[q]); r[4 + q] = f2bf(v1[q]); }
    *(bf16x8*)d = r;
}

// ---------------- GEMM1: Bu[m][n] = u[m][:].Bw[n][:], fused chunk-end reduce ----------------
// BM=64, BN=128, BK=64, 16 iters. A reg-staged fp32->bf16 into 2-buf LDS;
// B fragments DIRECT from L2-resident tiled Bwt into regs (1 tile ahead).
// One lgkm0+barrier per iter; no gload_lds, no manual vmcnt.
__global__ __launch_bounds__(256, 2) void gemm1(const float* __restrict__ u,
                                                const short* __restrict__ Bwt,
                                                const float* __restrict__ W,
                                                short* __restrict__ Bu,
                                                float* __restrict__ ends) {
    __shared__ short Ash[2][64 * 64];       // 8KB/buf: [row][8 chunks of 8, XOR-swz]
    const int tid = threadIdx.x;
    const int lane = tid & 63, wave = tid >> 6;
    const int lr = lane & 15, kq = lane >> 4;
    const int wr = wave >> 1, wc = wave & 1;
    const int wg = ((blockIdx.x & 7) << 6) + (blockIdx.x >> 3);  // 512 = 8*64 bijective
    const int cb = wg & 1, strip = wg >> 1;
    const int m0 = strip * 64, n0 = cb * 128;

    const int a_r = tid >> 4, a_k = (tid & 15) * 4;
    const float* au = u + (size_t)(m0 + a_r) * D_MODEL + a_k;
    const int a_ch = (tid & 15) >> 1, a_half = (tid & 1) * 4;
    const short* bg = Bwt + (size_t)cb * 16 * 8192;

    f32x4 acc[2][4] = {};
    f32x4 ar0[4], ar1[4], ar2[4];
    bf16x8 bfr[2][2][4];                    // [buf][ks][j]

    #define LOADA(SET, KT)                                                       \
        do { _Pragma("unroll")                                                   \
             for (int i = 0; i < 4; ++i)                                         \
                 SET[i] = *(const f32x4*)(au + (size_t)i * 16 * D_MODEL + (KT) * 64); } while (0)
    #define WRITEA(BUF, SET)                                                     \
        do { _Pragma("unroll")                                                   \
             for (int i = 0; i < 4; ++i) {                                       \
                 const int row = i * 16 + a_r;                                   \
                 s16x4 wv;                                                       \
                 _Pragma("unroll")                                               \
                 for (int e = 0; e < 4; ++e) wv[e] = f2bf(SET[i][e]);            \
                 *(s16x4*)&Ash[BUF][(row * 8 + (a_ch ^ (row & 7))) * 8 + a_half] = wv; \
             } } while (0)
    #define LOADB(BUF, KT)                                                       \
        do { _Pragma("unroll")                                                   \
             for (int ks = 0; ks < 2; ++ks)                                      \
                 _Pragma("unroll")                                               \
                 for (int j = 0; j < 4; ++j)                                     \
                     bfr[BUF][ks][j] = *(const bf16x8*)(bg + (size_t)(KT) * 8192 \
                         + ((ks * 4 + kq) * 128 + wc * 64 + j * 16 + lr) * 8); } while (0)

    // prologue: A(0) -> LDS, preload A(1),A(2) regs, B(0) regs
    LOADA(ar0, 0);
    WRITEA(0, ar0);
    LOADA(ar1, 1);
    LOADA(ar2, 2);
    LOADB(0, 0);
    WAITLGKM0;
    BARRIER();

    #pragma unroll
    for (int t = 0; t < 16; ++t) {
        if (t < 15) {                       // ds_write A(t+1) into buf (t+1)&1
            if (((t + 1) % 3) == 0)      WRITEA((t + 1) & 1, ar0);
            else if (((t + 1) % 3) == 1) WRITEA((t + 1) & 1, ar1);
            else                         WRITEA((t + 1) & 1, ar2);
        }
        if (t + 3 <= 15) {                  // refill the A reg set just consumed
            if (((t + 3) % 3) == 0)      LOADA(ar0, t + 3);
            else if (((t + 3) % 3) == 1) LOADA(ar1, t + 3);
            else                         LOADA(ar2, t + 3);
        }
        bf16x8 af[2][2];
        #pragma unroll
        for (int ks = 0; ks < 2; ++ks)
            #pragma unroll
            for (int i = 0; i < 2; ++i) {
                const int row = wr * 32 + i * 16 + lr;
                af[ks][i] = *(const bf16x8*)&Ash[t & 1][(row * 8 + ((ks * 4 + kq) ^ (row & 7))) * 8];
            }
        if (t < 15) LOADB((t + 1) & 1, t + 1);   // next B tile flies under MFMA
        #pragma unroll
        for (int ks = 0; ks < 2; ++ks)
            #pragma unroll
            for (int i = 0; i < 2; ++i)
                #pragma unroll
                for (int j = 0; j < 4; ++j)
                    acc[i][j] = __builtin_amdgcn_mfma_f32_16x16x32_bf16(bfr[t & 1][ks][j], af[ks][i], acc[i][j], 0, 0, 0);
        WAITLGKM0;                           // ds_writes drained before publishing
        BARRIER();
    }
    #undef LOADA
    #undef WRITEA
    #undef LOADB

    // Bu stores (swapped layout: m=lr-row, 4 consecutive n per f32x4)
    #pragma unroll
    for (int i = 0; i < 2; ++i) {
        const int m = m0 + wr * 32 + i * 16 + lr;
        #pragma unroll
        for (int j = 0; j < 4; ++j) {
            const int n = n0 + wc * 64 + j * 16 + kq * 4;
            s16x4 st;
            #pragma unroll
            for (int r = 0; r < 4; ++r) st[r] = f2bf(acc[i][j][r]);
            *(s16x4*)(Bu + (size_t)m * STATE_N + n) = st;
        }
    }

    // fused chunk-end reduce: ends[cg][n] = sum_row lam^(31-row)*Bu
    float part[4][4];
    #pragma unroll
    for (int j = 0; j < 4; ++j) {
        const int nb = n0 + wc * 64 + j * 16 + kq * 4;
        const f32x4 w0 = *(const f32x4*)(W + (size_t)lr * 256 + nb);
        const f32x4 w1 = *(const f32x4*)(W + (size_t)(16 + lr) * 256 + nb);
        #pragma unroll
        for (int r = 0; r < 4; ++r)
            part[j][r] = w0[r] * acc[0][j][r] + w1[r] * acc[1][j][r];
    }
    #pragma unroll
    for (int m = 1; m <= 8; m <<= 1)
        #pragma unroll
        for (int j = 0; j < 4; ++j)
            #pragma unroll
            for (int r = 0; r < 4; ++r)
                part[j][r] += __shfl_xor(part[j][r], m, 64);
    if (lr == 0) {
        const int cg = strip * 2 + wr;
        #pragma unroll
        for (int j = 0; j < 4; ++j) {
            f32x4 e;
            #pragma unroll
            for (int r = 0; r < 4; ++r) e[r] = part[j][r];
            *(f32x4*)(ends + (size_t)cg * STATE_N + n0 + wc * 64 + j * 16 + kq * 4) = e;
        }
    }
}

// ---------------- GEMM2 (fused scan): h = scan(Bu), y = h.Cw^T + D*u ----------------
// Block 64r x 64c, 32KB LDS (A only), 4 blocks/CU. Stage Bu tiles via gload_lds,
// in-LDS seeded scan, then barrier-free MFMA loop with B fragments direct from
// L2-resident Cwt (regs, 1 tile ahead). Vector u/y epilogue.
__global__ __launch_bounds__(256, 4) void gemm2(const short* __restrict__ Bu,
                                                const short* __restrict__ Cwt,
                                                const float* __restrict__ ll,
                                                const float* __restrict__ carries,
                                                const float* __restrict__ u,
                                                const float* __restrict__ Dv,
                                                float* __restrict__ y) {
    __shared__ short Ash[4][64 * 64];      // 32KB: [tile][row][64 shorts], chunk-XOR swz
    const int tid = threadIdx.x;
    const int lane = tid & 63, wave = tid >> 6;
    const int lr = lane & 15, kq = lane >> 4;
    const int wr = wave >> 1, wc = wave & 1;
    const int wg = ((blockIdx.x & 7) << 9) + (blockIdx.x >> 3);  // 4096 = 8*512 bijective
    const int cb = wg & 15, strip = wg >> 4;
    const int m0 = strip * 64, n0 = cb * 64;

    // scan chain assignment: thread -> (chunk-half, col-pair)
    const int ch = tid >> 7;
    const int cp = tid & 127;
    const int st = cp >> 5;
    const int c0 = (2 * cp) & 63;
    const int scc = c0 >> 3, scw = c0 & 7;

    const float2 lraw = *(const float2*)(ll + 2 * cp);
    const float2 car2 = *(const float2*)(carries + (size_t)(strip * 2 + ch) * STATE_N + 2 * cp);

    const int aslot0 = wave * 128 + lane, aslot1 = aslot0 + 64;
    const int arow0 = aslot0 >> 3, arow1 = aslot1 >> 3;
    const int ac = lane & 7;
    const short* ag0 = Bu + (size_t)(m0 + arow0) * STATE_N + ((ac ^ (arow0 & 7)) << 3);
    const short* ag1 = Bu + (size_t)(m0 + arow1) * STATE_N + ((ac ^ (arow1 & 7)) << 3);
    const short* bg = Cwt + (size_t)cb * 4096 * 4;

    #pragma unroll
    for (int t = 0; t < 4; ++t) {
        GLOAD_LDS16(ag0 + t * 64, (char*)&Ash[t][0] + aslot0 * 16);
        GLOAD_LDS16(ag1 + t * 64, (char*)&Ash[t][0] + aslot1 * 16);
    }
    WAITVM0;
    BARRIER();

    bf16x8 bfr[2][2][2];                   // [buf][ks][j]
    #define LOADB2(BUF, T)                                                       \
        do { _Pragma("unroll")                                                   \
             for (int ks = 0; ks < 2; ++ks)                                      \
                 _Pragma("unroll")                                               \
                 for (int j = 0; j < 2; ++j)                                     \
                     bfr[BUF][ks][j] = *(const bf16x8*)(bg + (size_t)(T) * 4096  \
                         + (((ks << 2) | kq) * 64 + wc * 32 + j * 16 + lr) * 8); } while (0)

    LOADB2(0, 0);                          // flies under the scan

    // ---- in-LDS seeded scan ----
    {
        const float lam0 = sigmoidf(lraw.x), lam1 = sigmoidf(lraw.y);
        s16x2 rv[32];
        #pragma unroll
        for (int i = 0; i < 32; ++i)
            rv[i] = *(const s16x2*)&Ash[st][(ch * 32 + i) * 64 + ((scc ^ (i & 7)) << 3) + scw];
        float h0 = car2.x, h1 = car2.y;
        #pragma unroll
        for (int i = 0; i < 32; ++i) {
            h0 = fmaf(lam0, h0, bf2f(rv[i][0]));
            h1 = fmaf(lam1, h1, bf2f(rv[i][1]));
            s16x2 o; o[0] = f2bf(h0); o[1] = f2bf(h1);
            rv[i] = o;
        }
        #pragma unroll
        for (int i = 0; i < 32; ++i)
            *(s16x2*)&Ash[st][(ch * 32 + i) * 64 + ((scc ^ (i & 7)) << 3) + scw] = rv[i];
    }
    WAITLGKM0;
    BARRIER();

    // ---- barrier-free MFMA loop (Ash read-only from here) ----
    f32x4 acc[2][2] = {};
    #pragma unroll
    for (int t = 0; t < 4; ++t) {
        bf16x8 af[2][2];
        #pragma unroll
        for (int ks = 0; ks < 2; ++ks)
            #pragma unroll
            for (int i = 0; i < 2; ++i) {
                const int row = wr * 32 + i * 16 + lr;
                af[ks][i] = *(const bf16x8*)&Ash[t][row * 64 + ((((ks << 2) | kq) ^ (row & 7)) << 3)];
            }
        if (t < 3) LOADB2((t + 1) & 1, t + 1);
        #pragma unroll
        for (int ks = 0; ks < 2; ++ks)
            #pragma unroll
            for (int i = 0; i < 2; ++i)
                #pragma unroll
                for (int j = 0; j < 2; ++j)
                    acc[i][j] = __builtin_amdgcn_mfma_f32_16x16x32_bf16(bfr[t & 1][ks][j], af[ks][i], acc[i][j], 0, 0, 0);
    }
    #undef LOADB2

    #pragma unroll
    for (int i = 0; i < 2; ++i) {
        const int m = m0 + wr * 32 + i * 16 + lr;
        #pragma unroll
        for (int j = 0; j < 2; ++j) {
            const int n = n0 + wc * 32 + j * 16 + kq * 4;
            const size_t o = (size_t)m * D_MODEL + n;
            const f32x4 uv = *(const f32x4*)(u + o);
            const f32x4 dv = *(const f32x4*)(Dv + n);
            f32x4 rv;
            #pragma unroll
            for (int q = 0; q < 4; ++q) rv[q] = fmaf(dv[q], uv[q], acc[i][j][q]);
            *(f32x4*)(y + o) = rv;
        }
    }
}

// ---------------- Scan pass 2: carry scan across chunks ----------------
__global__ void scan_carry(const float* __restrict__ ends,
                           const float* __restrict__ log_lambda,
                           float* __restrict__ carries) {
    const int n = threadIdx.x;
    const int b = blockIdx.x;
    const float lam = sigmoidf(log_lambda[n]);
    const float lamC = powf(lam, (float)CHUNK);
    float carry = 0.0f;
    #pragma unroll 16
    for (int c = 0; c < NCHUNK; ++c) {
        const size_t o = ((size_t)(b * NCHUNK + c)) * STATE_N + n;
        carries[o] = carry;
        carry = fmaf(lamC, carry, ends[o]);
    }
}

extern "C" void kernel_launch(void* const* d_in, const int* in_sizes, int n_in,
                              void* d_out, int out_size, void* d_ws, size_t ws_size,
                              hipStream_t stream) {
    const float* u  = (const float*)d_in[0];
    const float* ll = (const float*)d_in[1];
    const float* Bw = (const float*)d_in[2];
    const float* Cw = (const float*)d_in[3];
    const float* Dv = (const float*)d_in[4];
    float* y = (float*)d_out;

    char* ws = (char*)d_ws;
    size_t off = 0;
    short* Bwt = (short*)(ws + off); off += (size_t)STATE_N * D_MODEL * 2;      // 512 KB
    short* Cwt = (short*)(ws + off); off += (size_t)D_MODEL * STATE_N * 2;      // 512 KB
    float* W   = (float*)(ws + off); off += (size_t)32 * STATE_N * 4;           // 32 KB
    short* Bu  = (short*)(ws + off); off += (size_t)M_TOTAL * STATE_N * 2;      // 8 MB
    float* ends = (float*)(ws + off); off += (size_t)BATCH * NCHUNK * STATE_N * 4;
    float* carries = (float*)(ws + off);

    prep<<<288, 256, 0, stream>>>(Bw, Cw, ll, Bwt, Cwt, W);
    gemm1<<<512, 256, 0, stream>>>(u, Bwt, W, Bu, ends);
    scan_carry<<<BATCH, STATE_N, 0, stream>>>(ends, ll, carries);
    gemm2<<<4096, 256, 0, stream>>>(Bu, Cwt, ll, carries, u, Dv, y);
}